// Round 5
// baseline (301.702 us; speedup 1.0000x reference)
//
#include <hip/hip_runtime.h>
#include <stdint.h>

#define M_DIM 4096
#define T_DIM 2048
#define N_OUT 2024
#define N_PAD 2048
#define WIN   25
#define K_DIM 4096

typedef short bf16x8 __attribute__((ext_vector_type(8)));
typedef float f32x4  __attribute__((ext_vector_type(4)));

__device__ __forceinline__ unsigned short f2bf(float x) {
  unsigned u = __float_as_uint(x);
  u += 0x7FFF + ((u >> 16) & 1);           // round-to-nearest-even
  return (unsigned short)(u >> 16);
}
__device__ __forceinline__ float bf2f(unsigned short h) {
  return __uint_as_float(((unsigned)h) << 16);
}

__device__ __forceinline__ void gl2lds16(const void* g, void* l) {
  // 16B-wide async global->LDS; HW dest = wave-uniform base + lane*16
  __builtin_amdgcn_global_load_lds(
      (const __attribute__((address_space(1))) unsigned int*)g,
      (__attribute__((address_space(3))) unsigned int*)l, 16, 0, 0);
}

// ---------- Kernel 1: Wb = bf16(sigmoid(alphas)), diagonal -> 0 ----------
__global__ __launch_bounds__(256) void k_wcast(const float* __restrict__ alphas,
                                               unsigned short* __restrict__ Wb) {
  size_t i8 = ((size_t)blockIdx.x * 256 + threadIdx.x) * 8;
  const float4 v0 = *(const float4*)(alphas + i8);
  const float4 v1 = *(const float4*)(alphas + i8 + 4);
  int row = (int)(i8 >> 12);
  int col = (int)(i8 & 4095);
  float a[8] = {v0.x, v0.y, v0.z, v0.w, v1.x, v1.y, v1.z, v1.w};
  ushort4 o[2];
  unsigned short* op = (unsigned short*)o;
#pragma unroll
  for (int j = 0; j < 8; ++j) {
    float w = (row == col + j) ? 0.f : 1.f / (1.f + __expf(-a[j]));
    op[j] = f2bf(w);
  }
  *(uint4*)(Wb + i8) = *(uint4*)o;
}

// ---------- Kernel 2: S = bf16(softplus(depthwise_conv(ys, repro))) ----------
__global__ __launch_bounds__(256) void k_conv(const float* __restrict__ ys,
                                              const float* __restrict__ repro,
                                              unsigned short* __restrict__ Sbf) {
  __shared__ float sy[256 + WIN - 1];
  __shared__ float sr[WIN];
  int m = blockIdx.y;
  int j0 = blockIdx.x * 256;
  int tid = threadIdx.x;
  sy[tid] = ys[(size_t)m * T_DIM + j0 + tid];
  if (tid < WIN - 1) {
    int jj = j0 + 256 + tid;
    sy[256 + tid] = (jj < T_DIM) ? ys[(size_t)m * T_DIM + jj] : 0.f;
  }
  if (tid < WIN) sr[tid] = repro[m * WIN + tid];
  __syncthreads();
  int j = j0 + tid;
  float z = 0.f;
#pragma unroll
  for (int k = 0; k < WIN; ++k) z += sy[tid + k] * sr[k];
  float sp = fmaxf(z, 0.f) + log1pf(__expf(-fabsf(z)));
  Sbf[(size_t)m * N_PAD + j] = (j < N_OUT) ? f2bf(sp) : (unsigned short)0;
}

// ---------- Kernel 3: BT[n][k] = bf16(ys[k][n+24]), zero-pad n>=2024 ----------
__global__ __launch_bounds__(256) void k_transpose(const float* __restrict__ ys,
                                                   unsigned short* __restrict__ BT) {
  __shared__ float t[64][65];
  int n0 = blockIdx.x * 64;
  int k0 = blockIdx.y * 64;
  int tx = threadIdx.x;  // 0..63
  int ty = threadIdx.y;  // 0..3
#pragma unroll
  for (int r = 0; r < 16; ++r) {
    int kk = k0 + ty + r * 4;
    int n = n0 + tx;
    t[ty + r * 4][tx] = (n < N_OUT) ? ys[(size_t)kk * T_DIM + n + (WIN - 1)] : 0.f;
  }
  __syncthreads();
#pragma unroll
  for (int r = 0; r < 16; ++r) {
    int n = n0 + ty + r * 4;
    int kk = k0 + tx;
    BT[(size_t)n * K_DIM + kk] = f2bf(t[tx][ty + r * 4]);
  }
}

// ---------- Kernel 4: split-K GEMM. z=0 half -> fp32 into out (stride 2024),
//            z=1 half -> bf16 into Cp1 (stride 2048). R3 single-buffer
//            structure (dbuf regressed, R4); XOR swizzle keeps conflicts 0.
//            1024 blocks = 4 independent blocks/CU for latency overlap. ----------
__global__ __launch_bounds__(256) void k_gemm(const unsigned short* __restrict__ Wb,
                                              const unsigned short* __restrict__ BT,
                                              unsigned short* __restrict__ Cp1,
                                              float* __restrict__ out) {
  __shared__ __align__(16) unsigned short lA[128 * 32];
  __shared__ __align__(16) unsigned short lB[128 * 32];
  const int tid  = threadIdx.x;
  const int wave = tid >> 6;          // 0..3
  const int lane = tid & 63;
  const int wm = wave >> 1, wn = wave & 1;
  const int m16  = lane & 15;
  const int quad = lane >> 4;
  const int tileM = blockIdx.y * 128;
  const int tileN = blockIdx.x * 128;
  const int kz    = blockIdx.z;       // 0..1 (K half)

  // read-side swizzled fragment offsets (bytes)
  const int swz   = ((quad ^ ((m16 >> 1) & 3)) << 4);
  const int offA0 = (wm * 64 + m16) * 64 + swz;            // + i*1024
  const int offB0 = (wn * 64 + m16) * 64 + swz;            // + j*1024

  // staging: 2 chunks/thread/matrix; global addr carries the XOR swizzle
  const char* gA[2];
  const char* gB[2];
  char* ldsA[2];
  char* ldsB[2];
#pragma unroll
  for (int c = 0; c < 2; ++c) {
    int o  = c * 4096 + wave * 1024 + lane * 16;
    int r  = o >> 6;                    // LDS row 0..127
    int cc = (o >> 4) & 3;              // LDS chunk slot
    int q  = cc ^ ((r >> 1) & 3);       // logical (global) chunk
    gA[c] = (const char*)Wb + (((size_t)(tileM + r) * K_DIM) << 1) + q * 16;
    gB[c] = (const char*)BT + (((size_t)(tileN + r) * K_DIM) << 1) + q * 16;
    ldsA[c] = (char*)lA + c * 4096 + wave * 1024;   // wave-uniform base
    ldsB[c] = (char*)lB + c * 4096 + wave * 1024;
  }

  f32x4 acc[4][4];
#pragma unroll
  for (int i = 0; i < 4; ++i)
#pragma unroll
    for (int j = 0; j < 4; ++j) acc[i][j] = f32x4{0.f, 0.f, 0.f, 0.f};

  const int ktBeg = kz * (K_DIM / 64);        // 64 k-steps per half
  const int ktEnd = ktBeg + (K_DIM / 64);
  for (int kt = ktBeg; kt < ktEnd; ++kt) {
    const size_t kb = (size_t)kt * 64;  // 32 bf16 = 64 bytes
#pragma unroll
    for (int c = 0; c < 2; ++c) {
      gl2lds16(gA[c] + kb, ldsA[c]);
      gl2lds16(gB[c] + kb, ldsB[c]);
    }
    __syncthreads();
    bf16x8 aF[4], bF[4];
#pragma unroll
    for (int i = 0; i < 4; ++i) {
      aF[i] = *(const bf16x8*)((const char*)lA + offA0 + i * 1024);
      bF[i] = *(const bf16x8*)((const char*)lB + offB0 + i * 1024);
    }
#pragma unroll
    for (int i = 0; i < 4; ++i)
#pragma unroll
      for (int j = 0; j < 4; ++j)
        acc[i][j] = __builtin_amdgcn_mfma_f32_16x16x32_bf16(aF[i], bF[j], acc[i][j], 0, 0, 0);
    __syncthreads();
  }

  // Partial store. z=0: fp32 into out (row stride N_OUT, guard gn);
  //                z=1: bf16 into Cp1 (row stride N_PAD, no guard needed).
  if (kz == 0) {
#pragma unroll
    for (int j = 0; j < 4; ++j) {
      int gn = tileN + wn * 64 + j * 16 + m16;
      if (gn >= N_OUT) continue;
#pragma unroll
      for (int i = 0; i < 4; ++i)
#pragma unroll
        for (int r = 0; r < 4; ++r) {
          int gm = tileM + wm * 64 + i * 16 + quad * 4 + r;
          out[(size_t)gm * N_OUT + gn] = acc[i][j][r];
        }
    }
  } else {
#pragma unroll
    for (int j = 0; j < 4; ++j) {
      int gn = tileN + wn * 64 + j * 16 + m16;
#pragma unroll
      for (int i = 0; i < 4; ++i)
#pragma unroll
        for (int r = 0; r < 4; ++r) {
          int gm = tileM + wm * 64 + i * 16 + quad * 4 + r;
          Cp1[(size_t)gm * N_PAD + gn] = f2bf(acc[i][j][r]);
        }
    }
  }
}

// ---------- Kernel 5: out = softplus(b0+b1*t) * (S + out + Cp1) ----------
__global__ __launch_bounds__(256) void k_epi(const unsigned short* __restrict__ Cp1,
                                             const unsigned short* __restrict__ Sbf,
                                             const float* __restrict__ b0,
                                             const float* __restrict__ b1,
                                             float* __restrict__ out) {
  int row = blockIdx.x;
  int c8  = threadIdx.x * 8;
  if (c8 >= N_OUT) return;            // threads 253..255 idle
  float vb0 = b0[row], vb1 = b1[row];
  uint4 p1 = *(const uint4*)(Cp1 + (size_t)row * N_PAD + c8);
  uint4 sv = *(const uint4*)(Sbf + (size_t)row * N_PAD + c8);
  const unsigned short* p1s = (const unsigned short*)&p1;
  const unsigned short* svs = (const unsigned short*)&sv;
  float* orow = out + (size_t)row * N_OUT + c8;
  float4 o0 = *(const float4*)orow;
  float4 o1 = *(const float4*)(orow + 4);
  float oc[8] = {o0.x, o0.y, o0.z, o0.w, o1.x, o1.y, o1.z, o1.w};
  float res[8];
#pragma unroll
  for (int e = 0; e < 8; ++e) {
    float x = vb0 + vb1 * (float)(c8 + e + WIN);
    float beta = fmaxf(x, 0.f) + log1pf(__expf(-fabsf(x)));
    res[e] = beta * (bf2f(svs[e]) + oc[e] + bf2f(p1s[e]));
  }
  *(float4*)orow = float4{res[0], res[1], res[2], res[3]};
  *(float4*)(orow + 4) = float4{res[4], res[5], res[6], res[7]};
}

extern "C" void kernel_launch(void* const* d_in, const int* in_sizes, int n_in,
                              void* d_out, int out_size, void* d_ws, size_t ws_size,
                              hipStream_t stream) {
  const float* ys     = (const float*)d_in[0];
  const float* alphas = (const float*)d_in[1];
  const float* repro  = (const float*)d_in[2];
  const float* b0     = (const float*)d_in[3];
  const float* b1     = (const float*)d_in[4];
  float* out = (float*)d_out;

  char* ws = (char*)d_ws;
  unsigned short* Wb  = (unsigned short*)ws;                                   // 32 MiB
  unsigned short* BT  = (unsigned short*)(ws + (size_t)M_DIM * K_DIM * 2);     // 16 MiB
  unsigned short* Sbf = (unsigned short*)(ws + (size_t)M_DIM * K_DIM * 2
                                             + (size_t)N_PAD * K_DIM * 2);     // 16 MiB
  unsigned short* Cp1 = (unsigned short*)(ws + (size_t)M_DIM * K_DIM * 2
                                             + (size_t)N_PAD * K_DIM * 2
                                             + (size_t)M_DIM * N_PAD * 2);    // 16 MiB

  k_wcast<<<(M_DIM * (size_t)K_DIM) / 8 / 256, 256, 0, stream>>>(alphas, Wb);
  k_conv<<<dim3(T_DIM / 256, M_DIM), 256, 0, stream>>>(ys, repro, Sbf);
  k_transpose<<<dim3(N_PAD / 64, K_DIM / 64), dim3(64, 4), 0, stream>>>(ys, BT);
  k_gemm<<<dim3(N_PAD / 128, M_DIM / 128, 2), 256, 0, stream>>>(Wb, BT, Cp1, out);
  k_epi<<<M_DIM, 256, 0, stream>>>(Cp1, Sbf, b0, b1, out);
}

// Round 6
// 284.220 us; speedup vs baseline: 1.0615x; 1.0615x over previous
//
#include <hip/hip_runtime.h>
#include <stdint.h>

#define M_DIM 4096
#define T_DIM 2048
#define N_OUT 2024
#define N_PAD 2048
#define WIN   25
#define K_DIM 4096

typedef short bf16x8 __attribute__((ext_vector_type(8)));
typedef float f32x4  __attribute__((ext_vector_type(4)));

__device__ __forceinline__ unsigned short f2bf(float x) {
  unsigned u = __float_as_uint(x);
  u += 0x7FFF + ((u >> 16) & 1);           // round-to-nearest-even
  return (unsigned short)(u >> 16);
}
__device__ __forceinline__ float bf2f(unsigned short h) {
  return __uint_as_float(((unsigned)h) << 16);
}

__device__ __forceinline__ void gl2lds16(const void* g, void* l) {
  // 16B-wide async global->LDS; HW dest = wave-uniform base + lane*16
  __builtin_amdgcn_global_load_lds(
      (const __attribute__((address_space(1))) unsigned int*)g,
      (__attribute__((address_space(3))) unsigned int*)l, 16, 0, 0);
}

// ---------- Kernel 1: Wb = bf16(sigmoid(alphas)), diagonal -> 0 ----------
__global__ __launch_bounds__(256) void k_wcast(const float* __restrict__ alphas,
                                               unsigned short* __restrict__ Wb) {
  size_t i8 = ((size_t)blockIdx.x * 256 + threadIdx.x) * 8;
  const float4 v0 = *(const float4*)(alphas + i8);
  const float4 v1 = *(const float4*)(alphas + i8 + 4);
  int row = (int)(i8 >> 12);
  int col = (int)(i8 & 4095);
  float a[8] = {v0.x, v0.y, v0.z, v0.w, v1.x, v1.y, v1.z, v1.w};
  ushort4 o[2];
  unsigned short* op = (unsigned short*)o;
#pragma unroll
  for (int j = 0; j < 8; ++j) {
    float w = (row == col + j) ? 0.f : 1.f / (1.f + __expf(-a[j]));
    op[j] = f2bf(w);
  }
  *(uint4*)(Wb + i8) = *(uint4*)o;
}

// ---------- Kernel 2: S = bf16(softplus(depthwise_conv(ys, repro))) ----------
__global__ __launch_bounds__(256) void k_conv(const float* __restrict__ ys,
                                              const float* __restrict__ repro,
                                              unsigned short* __restrict__ Sbf) {
  __shared__ float sy[256 + WIN - 1];
  __shared__ float sr[WIN];
  int m = blockIdx.y;
  int j0 = blockIdx.x * 256;
  int tid = threadIdx.x;
  sy[tid] = ys[(size_t)m * T_DIM + j0 + tid];
  if (tid < WIN - 1) {
    int jj = j0 + 256 + tid;
    sy[256 + tid] = (jj < T_DIM) ? ys[(size_t)m * T_DIM + jj] : 0.f;
  }
  if (tid < WIN) sr[tid] = repro[m * WIN + tid];
  __syncthreads();
  int j = j0 + tid;
  float z = 0.f;
#pragma unroll
  for (int k = 0; k < WIN; ++k) z += sy[tid + k] * sr[k];
  float sp = fmaxf(z, 0.f) + log1pf(__expf(-fabsf(z)));
  Sbf[(size_t)m * N_PAD + j] = (j < N_OUT) ? f2bf(sp) : (unsigned short)0;
}

// ---------- Kernel 3: BT[n][k] = bf16(ys[k][n+24]), zero-pad n>=2024 ----------
__global__ __launch_bounds__(256) void k_transpose(const float* __restrict__ ys,
                                                   unsigned short* __restrict__ BT) {
  __shared__ float t[64][65];
  int n0 = blockIdx.x * 64;
  int k0 = blockIdx.y * 64;
  int tx = threadIdx.x;  // 0..63
  int ty = threadIdx.y;  // 0..3
#pragma unroll
  for (int r = 0; r < 16; ++r) {
    int kk = k0 + ty + r * 4;
    int n = n0 + tx;
    t[ty + r * 4][tx] = (n < N_OUT) ? ys[(size_t)kk * T_DIM + n + (WIN - 1)] : 0.f;
  }
  __syncthreads();
#pragma unroll
  for (int r = 0; r < 16; ++r) {
    int n = n0 + ty + r * 4;
    int kk = k0 + tx;
    BT[(size_t)n * K_DIM + kk] = f2bf(t[tx][ty + r * 4]);
  }
}

// ---------- Kernel 4: C = Wb @ BT^T, out = beta * (S + C) ----------
// R6: BK=64 — amortize the fixed per-barrier cost (drain+barrier ~500cy,
// shown invariant across R2/R3/R5 concurrency changes) over 2x the compute.
// 64 ksteps, 128 barriers. LDS rows = 128B (64 bf16, 8x16B chunks);
// XOR swizzle slot = chunk ^ (row&7), applied on the global source address.
__global__ __launch_bounds__(256) void k_gemm(const unsigned short* __restrict__ Wb,
                                              const unsigned short* __restrict__ BT,
                                              const unsigned short* __restrict__ Sbf,
                                              const float* __restrict__ b0,
                                              const float* __restrict__ b1,
                                              float* __restrict__ out) {
  __shared__ __align__(16) unsigned short lA[128 * 64];   // 16 KB
  __shared__ __align__(16) unsigned short lB[128 * 64];   // 16 KB
  const int tid  = threadIdx.x;
  const int wave = tid >> 6;          // 0..3
  const int lane = tid & 63;
  const int wm = wave >> 1, wn = wave & 1;
  const int m16  = lane & 15;
  const int quad = lane >> 4;
  const int tileM = blockIdx.y * 128;
  const int tileN = blockIdx.x * 128;

  // read-side swizzled fragment offsets (bytes).
  // row = wm*64 + i*16 + m16 -> row&7 == m16&7 (independent of i).
  // khalf h: logical chunk = h*4 + quad; slot = chunk ^ (m16&7).
  const int baseA = (wm * 64 + m16) * 128;
  const int baseB = (wn * 64 + m16) * 128;
  int sOf[2];
#pragma unroll
  for (int h = 0; h < 2; ++h) sOf[h] = ((h * 4 + quad) ^ (m16 & 7)) * 16;

  // staging: 4 chunks/thread/matrix; global addr carries the XOR swizzle
  const char* gA[4];
  const char* gB[4];
  char* ldsA[4];
  char* ldsB[4];
#pragma unroll
  for (int c = 0; c < 4; ++c) {
    int o  = c * 4096 + wave * 1024 + lane * 16;  // 0..16383
    int r  = o >> 7;                    // LDS row 0..127 (128B rows)
    int s  = (o >> 4) & 7;              // LDS chunk slot
    int q  = s ^ (r & 7);               // logical (global) chunk
    gA[c] = (const char*)Wb + (((size_t)(tileM + r) * K_DIM) << 1) + q * 16;
    gB[c] = (const char*)BT + (((size_t)(tileN + r) * K_DIM) << 1) + q * 16;
    ldsA[c] = (char*)lA + c * 4096 + wave * 1024;   // wave-uniform base
    ldsB[c] = (char*)lB + c * 4096 + wave * 1024;
  }

  f32x4 acc[4][4];
#pragma unroll
  for (int i = 0; i < 4; ++i)
#pragma unroll
    for (int j = 0; j < 4; ++j) acc[i][j] = f32x4{0.f, 0.f, 0.f, 0.f};

  for (int kt = 0; kt < K_DIM / 64; ++kt) {
    const size_t kb = (size_t)kt * 128;  // 64 bf16 = 128 bytes
#pragma unroll
    for (int c = 0; c < 4; ++c) {
      gl2lds16(gA[c] + kb, ldsA[c]);
      gl2lds16(gB[c] + kb, ldsB[c]);
    }
    __syncthreads();
#pragma unroll
    for (int h = 0; h < 2; ++h) {
      bf16x8 aF[4], bF[4];
#pragma unroll
      for (int i = 0; i < 4; ++i) {
        aF[i] = *(const bf16x8*)((const char*)lA + baseA + i * 2048 + sOf[h]);
        bF[i] = *(const bf16x8*)((const char*)lB + baseB + i * 2048 + sOf[h]);
      }
#pragma unroll
      for (int i = 0; i < 4; ++i)
#pragma unroll
        for (int j = 0; j < 4; ++j)
          acc[i][j] = __builtin_amdgcn_mfma_f32_16x16x32_bf16(aF[i], bF[j], acc[i][j], 0, 0, 0);
    }
    __syncthreads();
  }

  // Epilogue: out[gm][gn] = softplus(b0+b1*(gn+25)) * (S[gm][gn] + C)
#pragma unroll
  for (int j = 0; j < 4; ++j) {
    int gn = tileN + wn * 64 + j * 16 + m16;
    if (gn >= N_OUT) continue;
    float tval = (float)(gn + WIN);
#pragma unroll
    for (int i = 0; i < 4; ++i) {
#pragma unroll
      for (int r = 0; r < 4; ++r) {
        int gm = tileM + wm * 64 + i * 16 + quad * 4 + r;
        float x = b0[gm] + b1[gm] * tval;
        float beta = fmaxf(x, 0.f) + log1pf(__expf(-fabsf(x)));
        float s = bf2f(Sbf[(size_t)gm * N_PAD + gn]);
        out[(size_t)gm * N_OUT + gn] = beta * (s + acc[i][j][r]);
      }
    }
  }
}

extern "C" void kernel_launch(void* const* d_in, const int* in_sizes, int n_in,
                              void* d_out, int out_size, void* d_ws, size_t ws_size,
                              hipStream_t stream) {
  const float* ys     = (const float*)d_in[0];
  const float* alphas = (const float*)d_in[1];
  const float* repro  = (const float*)d_in[2];
  const float* b0     = (const float*)d_in[3];
  const float* b1     = (const float*)d_in[4];
  float* out = (float*)d_out;

  char* ws = (char*)d_ws;
  unsigned short* Wb  = (unsigned short*)ws;                                   // 32 MiB
  unsigned short* BT  = (unsigned short*)(ws + (size_t)M_DIM * K_DIM * 2);     // 16 MiB
  unsigned short* Sbf = (unsigned short*)(ws + (size_t)M_DIM * K_DIM * 2
                                             + (size_t)N_PAD * K_DIM * 2);     // 16 MiB

  k_wcast<<<(M_DIM * (size_t)K_DIM) / 8 / 256, 256, 0, stream>>>(alphas, Wb);
  k_conv<<<dim3(T_DIM / 256, M_DIM), 256, 0, stream>>>(ys, repro, Sbf);
  k_transpose<<<dim3(N_PAD / 64, K_DIM / 64), dim3(64, 4), 0, stream>>>(ys, BT);
  k_gemm<<<dim3(N_PAD / 128, M_DIM / 128), 256, 0, stream>>>(Wb, BT, Sbf, b0, b1, out);
}

// Round 7
// 263.789 us; speedup vs baseline: 1.1437x; 1.0774x over previous
//
#include <hip/hip_runtime.h>
#include <stdint.h>

#define M_DIM 4096
#define T_DIM 2048
#define N_OUT 2024
#define N_PAD 2048
#define WIN   25
#define K_DIM 4096

typedef float f32x4 __attribute__((ext_vector_type(4)));

__device__ __forceinline__ unsigned short f2bf(float x) {
  unsigned u = __float_as_uint(x);
  u += 0x7FFF + ((u >> 16) & 1);           // round-to-nearest-even
  return (unsigned short)(u >> 16);
}
__device__ __forceinline__ float bf2f(unsigned short h) {
  return __uint_as_float(((unsigned)h) << 16);
}

__device__ __forceinline__ void gl2lds16(const void* g, void* l) {
  // 16B-wide async global->LDS; HW dest = wave-uniform base + lane*16
  __builtin_amdgcn_global_load_lds(
      (const __attribute__((address_space(1))) unsigned int*)g,
      (__attribute__((address_space(3))) unsigned int*)l, 16, 0, 0);
}

// pack 4 floats -> 4 e4m3 bytes (one dword)
__device__ __forceinline__ int pk_fp8x4(float a, float b, float c, float d) {
  int w = __builtin_amdgcn_cvt_pk_fp8_f32(a, b, 0, false);
  w = __builtin_amdgcn_cvt_pk_fp8_f32(c, d, w, true);
  return w;
}

// ---------- Kernel 1: W8 = e4m3(sigmoid(alphas)), diagonal -> 0 ----------
__global__ __launch_bounds__(256) void k_wcast(const float* __restrict__ alphas,
                                               unsigned char* __restrict__ W8) {
  size_t i8 = ((size_t)blockIdx.x * 256 + threadIdx.x) * 8;
  const float4 v0 = *(const float4*)(alphas + i8);
  const float4 v1 = *(const float4*)(alphas + i8 + 4);
  int row = (int)(i8 >> 12);
  int col = (int)(i8 & 4095);
  float a[8] = {v0.x, v0.y, v0.z, v0.w, v1.x, v1.y, v1.z, v1.w};
  float w[8];
#pragma unroll
  for (int j = 0; j < 8; ++j)
    w[j] = (row == col + j) ? 0.f : 1.f / (1.f + __expf(-a[j]));
  int p0 = pk_fp8x4(w[0], w[1], w[2], w[3]);
  int p1 = pk_fp8x4(w[4], w[5], w[6], w[7]);
  *(uint2*)(W8 + i8) = uint2{(unsigned)p0, (unsigned)p1};
}

// ---------- Kernel 2: S = bf16(softplus(depthwise_conv(ys, repro))) ----------
__global__ __launch_bounds__(256) void k_conv(const float* __restrict__ ys,
                                              const float* __restrict__ repro,
                                              unsigned short* __restrict__ Sbf) {
  __shared__ float sy[256 + WIN - 1];
  __shared__ float sr[WIN];
  int m = blockIdx.y;
  int j0 = blockIdx.x * 256;
  int tid = threadIdx.x;
  sy[tid] = ys[(size_t)m * T_DIM + j0 + tid];
  if (tid < WIN - 1) {
    int jj = j0 + 256 + tid;
    sy[256 + tid] = (jj < T_DIM) ? ys[(size_t)m * T_DIM + jj] : 0.f;
  }
  if (tid < WIN) sr[tid] = repro[m * WIN + tid];
  __syncthreads();
  int j = j0 + tid;
  float z = 0.f;
#pragma unroll
  for (int k = 0; k < WIN; ++k) z += sy[tid + k] * sr[k];
  float sp = fmaxf(z, 0.f) + log1pf(__expf(-fabsf(z)));
  Sbf[(size_t)m * N_PAD + j] = (j < N_OUT) ? f2bf(sp) : (unsigned short)0;
}

// ---------- Kernel 3: BT8[n][k] = e4m3(ys[k][n+24]), zero-pad n>=2024 ----------
__global__ __launch_bounds__(256) void k_transpose(const float* __restrict__ ys,
                                                   unsigned char* __restrict__ BT8) {
  __shared__ float t[64][65];
  int n0 = blockIdx.x * 64;
  int k0 = blockIdx.y * 64;
  int tx = threadIdx.x;  // 0..63
  int ty = threadIdx.y;  // 0..3
#pragma unroll
  for (int r = 0; r < 16; ++r) {
    int kk = k0 + ty + r * 4;
    int n = n0 + tx;
    t[ty + r * 4][tx] = (n < N_OUT) ? ys[(size_t)kk * T_DIM + n + (WIN - 1)] : 0.f;
  }
  __syncthreads();
  int tid = ty * 64 + tx;
  int nl = tid >> 2;          // 0..63
  int kc = (tid & 3) * 16;    // 0,16,32,48
  unsigned wds[4];
#pragma unroll
  for (int w = 0; w < 4; ++w)
    wds[w] = (unsigned)pk_fp8x4(t[kc + 4 * w][nl], t[kc + 4 * w + 1][nl],
                                t[kc + 4 * w + 2][nl], t[kc + 4 * w + 3][nl]);
  *(uint4*)(BT8 + (size_t)(n0 + nl) * K_DIM + k0 + kc) =
      uint4{wds[0], wds[1], wds[2], wds[3]};
}

// ---------- Kernel 4: C = W8 @ BT8^T (fp8 MFMA), out = beta * (S + C) ----------
// R7: fp8 e4m3 operands — halves staged bytes/FLOP. Six rounds showed the
// invariant binding resource is per-CU staging ingest (~15.5 B/cy); dtype
// shrink is the only lever that cuts bytes without costing grid/occupancy.
// BK=64 fp8 = 16 KB/kstep (R3's best granularity), 64 ksteps, single buffer,
// R3 XOR chunk swizzle (4 lanes per 8B slot = 2/bank = conflict-free).
__global__ __launch_bounds__(256) void k_gemm(const unsigned char* __restrict__ W8,
                                              const unsigned char* __restrict__ BT8,
                                              const unsigned short* __restrict__ Sbf,
                                              const float* __restrict__ b0,
                                              const float* __restrict__ b1,
                                              float* __restrict__ out) {
  __shared__ __align__(16) unsigned char lA[128 * 64];   // 8 KB
  __shared__ __align__(16) unsigned char lB[128 * 64];   // 8 KB
  const int tid  = threadIdx.x;
  const int wave = tid >> 6;          // 0..3
  const int lane = tid & 63;
  const int wm = wave >> 1, wn = wave & 1;
  const int m16  = lane & 15;
  const int quad = lane >> 4;
  const int tileM = blockIdx.y * 128;
  const int tileN = blockIdx.x * 128;

  // fragment read offsets: row = w*64 + i*16 + m16, 64B rows (K=64 fp8).
  // MFMA h (k-half, K=32 each): lane needs bytes k = h*32 + quad*8 .. +7
  // chunk c = 2h + (quad>>1), swizzled slot = c ^ ((m16>>1)&3), sub = (quad&1)*8
  const int key  = (m16 >> 1) & 3;
  const int sub  = (quad & 1) * 8;
  const int rowA = (wm * 64 + m16) * 64;
  const int rowB = (wn * 64 + m16) * 64;
  int hOf[2];
#pragma unroll
  for (int h = 0; h < 2; ++h)
    hOf[h] = (((2 * h + (quad >> 1)) ^ key) << 4) + sub;

  // staging: 2 chunks/thread/matrix (8KB per matrix per kstep);
  // global addr carries the XOR swizzle
  const unsigned char* gA[2];
  const unsigned char* gB[2];
  unsigned char* ldsA[2];
  unsigned char* ldsB[2];
#pragma unroll
  for (int c = 0; c < 2; ++c) {
    int o  = c * 4096 + wave * 1024 + lane * 16;   // 0..8191
    int r  = o >> 6;                    // LDS row 0..127 (64B rows)
    int s  = (o >> 4) & 3;              // LDS chunk slot
    int q  = s ^ ((r >> 1) & 3);        // logical (global) chunk
    gA[c] = W8  + (size_t)(tileM + r) * K_DIM + q * 16;
    gB[c] = BT8 + (size_t)(tileN + r) * K_DIM + q * 16;
    ldsA[c] = lA + c * 4096 + wave * 1024;   // wave-uniform base
    ldsB[c] = lB + c * 4096 + wave * 1024;
  }

  f32x4 acc[4][4];
#pragma unroll
  for (int i = 0; i < 4; ++i)
#pragma unroll
    for (int j = 0; j < 4; ++j) acc[i][j] = f32x4{0.f, 0.f, 0.f, 0.f};

  for (int kt = 0; kt < K_DIM / 64; ++kt) {
    const size_t kb = (size_t)kt * 64;   // 64 fp8 = 64 bytes
#pragma unroll
    for (int c = 0; c < 2; ++c) {
      gl2lds16(gA[c] + kb, ldsA[c]);
      gl2lds16(gB[c] + kb, ldsB[c]);
    }
    __syncthreads();
#pragma unroll
    for (int h = 0; h < 2; ++h) {
      long long aF[4], bF[4];
#pragma unroll
      for (int i = 0; i < 4; ++i) {
        aF[i] = *(const long long*)(lA + rowA + i * 1024 + hOf[h]);
        bF[i] = *(const long long*)(lB + rowB + i * 1024 + hOf[h]);
      }
#pragma unroll
      for (int i = 0; i < 4; ++i)
#pragma unroll
        for (int j = 0; j < 4; ++j)
          acc[i][j] = __builtin_amdgcn_mfma_f32_16x16x32_fp8_fp8(
              aF[i], bF[j], acc[i][j], 0, 0, 0);
    }
    __syncthreads();
  }

  // Epilogue: out[gm][gn] = softplus(b0+b1*(gn+25)) * (S[gm][gn] + C)
#pragma unroll
  for (int j = 0; j < 4; ++j) {
    int gn = tileN + wn * 64 + j * 16 + m16;
    if (gn >= N_OUT) continue;
    float tval = (float)(gn + WIN);
#pragma unroll
    for (int i = 0; i < 4; ++i) {
#pragma unroll
      for (int r = 0; r < 4; ++r) {
        int gm = tileM + wm * 64 + i * 16 + quad * 4 + r;
        float x = b0[gm] + b1[gm] * tval;
        float beta = fmaxf(x, 0.f) + log1pf(__expf(-fabsf(x)));
        float s = bf2f(Sbf[(size_t)gm * N_PAD + gn]);
        out[(size_t)gm * N_OUT + gn] = beta * (s + acc[i][j][r]);
      }
    }
  }
}

extern "C" void kernel_launch(void* const* d_in, const int* in_sizes, int n_in,
                              void* d_out, int out_size, void* d_ws, size_t ws_size,
                              hipStream_t stream) {
  const float* ys     = (const float*)d_in[0];
  const float* alphas = (const float*)d_in[1];
  const float* repro  = (const float*)d_in[2];
  const float* b0     = (const float*)d_in[3];
  const float* b1     = (const float*)d_in[4];
  float* out = (float*)d_out;

  char* ws = (char*)d_ws;
  unsigned char*  W8  = (unsigned char*)ws;                                    // 16 MiB
  unsigned char*  BT8 = (unsigned char*)(ws + (size_t)M_DIM * K_DIM);          //  8 MiB
  unsigned short* Sbf = (unsigned short*)(ws + (size_t)M_DIM * K_DIM
                                             + (size_t)N_PAD * K_DIM);         // 16 MiB

  k_wcast<<<(M_DIM * (size_t)K_DIM) / 8 / 256, 256, 0, stream>>>(alphas, W8);
  k_conv<<<dim3(T_DIM / 256, M_DIM), 256, 0, stream>>>(ys, repro, Sbf);
  k_transpose<<<dim3(N_PAD / 64, K_DIM / 64), dim3(64, 4), 0, stream>>>(ys, BT8);
  k_gemm<<<dim3(N_PAD / 128, M_DIM / 128), 256, 0, stream>>>(W8, BT8, Sbf, b0, b1, out);
}